// Round 7
// baseline (7001.373 us; speedup 1.0000x reference)
//
#include <hip/hip_runtime.h>
#include <hip/hip_bf16.h>

#define NB    32768
#define NIN   1024
#define NHID  2048
#define NLAT  64
#define NEMB  4096
#define BETA  0.25f

#define FLTMAX 3.402823466e+38f

// ---- output layout (FLOAT32 elements — d_out is float*, ref dtype f32) ----
#define XR_OFF   0
#define ZE_OFF   33554432
#define ZQ_OFF   35651584
#define IDX_OFF  37748736
#define LOSS_OFF 37781504

// ---- ws layout: 512 loss partials only ----
#define PART_WS  0

static __device__ __forceinline__ void fma4(float4& acc, float s, const float4& wv) {
    acc.x += s * wv.x; acc.y += s * wv.y; acc.z += s * wv.z; acc.w += s * wv.w;
}

// ---------------- fused encoder + VQ ----------------
// 256 threads, 64 rows/block. thread (rg=t>>4, cg=t&15): rows rg+16i, cols cg*4..+3
__global__ __launch_bounds__(256)
void encvq_kernel(const float* __restrict__ x,  const float* __restrict__ w1,
                  const float* __restrict__ b1, const float* __restrict__ w2,
                  const float* __restrict__ b2, const float* __restrict__ cb,
                  float* __restrict__ out, float* __restrict__ partials) {
    float* ze_out  = out + ZE_OFF;
    float* zq_out  = out + ZQ_OFF;
    float* idx_out = out + IDX_OFF;

    __shared__ __align__(16) float smem[3 * 64 * 68];   // 52 KB
    float* xs = smem;
    float* wt = smem + 64 * 68;
    float* hs = smem + 2 * 64 * 68;
    float* zs = smem;                 // vq phase: aliases xs
    float* cbs = smem + 64 * 68;      // vq phase: [128*68] aliases wt+hs
    __shared__ float zsq[64];
    __shared__ float lred[64];
    __shared__ float eqs[128];
    __shared__ float rbest[64 * 17];
    __shared__ int   ridx[64 * 17];

    const int t = threadIdx.x;
    const int rg = t >> 4, cg = t & 15;
    const int brow = blockIdx.x * 64;

    // ---------------- phase 1: encoder ----------------
    float4 zacc[4];
#pragma unroll
    for (int i = 0; i < 4; i++) zacc[i] = make_float4(0.f, 0.f, 0.f, 0.f);

    for (int jc = 0; jc < NHID; jc += 64) {
        float4 hacc[4];
#pragma unroll
        for (int i = 0; i < 4; i++) hacc[i] = make_float4(0.f, 0.f, 0.f, 0.f);

        for (int kc = 0; kc < NIN; kc += 64) {
            __syncthreads();
#pragma unroll
            for (int jj = 0; jj < 4; jj++) {              // stage x tile [64][64]
                int e4 = t + 256 * jj;
                int r = e4 >> 4, c4 = (e4 & 15) * 4;
                *reinterpret_cast<float4*>(&xs[r * 68 + c4]) =
                    *reinterpret_cast<const float4*>(&x[(size_t)(brow + r) * NIN + kc + c4]);
            }
#pragma unroll
            for (int jj = 0; jj < 4; jj++) {              // stage w1 tile [64][64]
                int e4 = t + 256 * jj;
                int r = e4 >> 4, c4 = (e4 & 15) * 4;
                *reinterpret_cast<float4*>(&wt[r * 68 + c4]) =
                    *reinterpret_cast<const float4*>(&w1[(size_t)(kc + r) * NHID + jc + c4]);
            }
            __syncthreads();
#pragma unroll 16
            for (int k = 0; k < 64; k++) {
                float a0 = xs[(rg +  0) * 68 + k];
                float a1 = xs[(rg + 16) * 68 + k];
                float a2 = xs[(rg + 32) * 68 + k];
                float a3 = xs[(rg + 48) * 68 + k];
                float4 w4 = *reinterpret_cast<float4*>(&wt[k * 68 + cg * 4]);
                fma4(hacc[0], a0, w4); fma4(hacc[1], a1, w4);
                fma4(hacc[2], a2, w4); fma4(hacc[3], a3, w4);
            }
        }
        float4 bv = *reinterpret_cast<const float4*>(&b1[jc + cg * 4]);
#pragma unroll
        for (int i = 0; i < 4; i++) {
            float4 h;
            h.x = fmaxf(hacc[i].x + bv.x, 0.f);
            h.y = fmaxf(hacc[i].y + bv.y, 0.f);
            h.z = fmaxf(hacc[i].z + bv.z, 0.f);
            h.w = fmaxf(hacc[i].w + bv.w, 0.f);
            *reinterpret_cast<float4*>(&hs[(rg + 16 * i) * 68 + cg * 4]) = h;
        }
        __syncthreads();
#pragma unroll
        for (int jj = 0; jj < 4; jj++) {                  // stage w2 tile [64][64]
            int e4 = t + 256 * jj;
            int r = e4 >> 4, c4 = (e4 & 15) * 4;
            *reinterpret_cast<float4*>(&wt[r * 68 + c4]) =
                *reinterpret_cast<const float4*>(&w2[(size_t)(jc + r) * NLAT + c4]);
        }
        __syncthreads();
#pragma unroll 8
        for (int k = 0; k < 64; k++) {
            float a0 = hs[(rg +  0) * 68 + k];
            float a1 = hs[(rg + 16) * 68 + k];
            float a2 = hs[(rg + 32) * 68 + k];
            float a3 = hs[(rg + 48) * 68 + k];
            float4 w4 = *reinterpret_cast<float4*>(&wt[k * 68 + cg * 4]);
            fma4(zacc[0], a0, w4); fma4(zacc[1], a1, w4);
            fma4(zacc[2], a2, w4); fma4(zacc[3], a3, w4);
        }
    }
    __syncthreads();   // protect zs (= xs alias) overwrite
    float4 b2v = *reinterpret_cast<const float4*>(&b2[cg * 4]);
#pragma unroll
    for (int i = 0; i < 4; i++) {
        int row = brow + rg + 16 * i;
        float4 z = zacc[i];
        z.x += b2v.x; z.y += b2v.y; z.z += b2v.z; z.w += b2v.w;
        *reinterpret_cast<float4*>(&zs[(rg + 16 * i) * 68 + cg * 4]) = z;
        *reinterpret_cast<float4*>(&ze_out[(size_t)row * NLAT + cg * 4]) = z;
    }
    __syncthreads();

    // ---------------- phase 2: VQ ----------------
    if (t < 64) {
        float s = 0.f;
#pragma unroll 16
        for (int d = 0; d < 64; d++) { float v = zs[t * 68 + d]; s += v * v; }
        zsq[t] = s;
    }
    __syncthreads();
    float zr[4];
#pragma unroll
    for (int i = 0; i < 4; i++) zr[i] = zsq[rg + 16 * i];

    float best[4]; int bidx[4];
#pragma unroll
    for (int i = 0; i < 4; i++) { best[i] = FLTMAX; bidx[i] = 0; }

    for (int cc = 0; cc < NEMB; cc += 128) {
        __syncthreads();
#pragma unroll
        for (int jj = 0; jj < 8; jj++) {                  // stage codebook chunk [128][64]
            int e4 = t + 256 * jj;
            int r = e4 >> 4, c4 = (e4 & 15) * 4;
            *reinterpret_cast<float4*>(&cbs[r * 68 + c4]) =
                *reinterpret_cast<const float4*>(&cb[(size_t)(cc + r) * NLAT + c4]);
        }
        __syncthreads();
        if (t < 128) {                                    // in-LDS codebook norms
            float s = 0.f;
#pragma unroll 16
            for (int d = 0; d < 64; d++) { float v = cbs[t * 68 + d]; s += v * v; }
            eqs[t] = s;
        }
        __syncthreads();
        float dot[4][8];
#pragma unroll
        for (int i = 0; i < 4; i++)
#pragma unroll
            for (int j = 0; j < 8; j++) dot[i][j] = 0.f;
#pragma unroll 4
        for (int d4 = 0; d4 < 64; d4 += 4) {
            float4 zv[4];
#pragma unroll
            for (int i = 0; i < 4; i++)
                zv[i] = *reinterpret_cast<float4*>(&zs[(rg + 16 * i) * 68 + d4]);
#pragma unroll
            for (int j = 0; j < 8; j++) {
                float4 cv = *reinterpret_cast<float4*>(&cbs[(cg + 16 * j) * 68 + d4]);
#pragma unroll
                for (int i = 0; i < 4; i++) {
                    dot[i][j] += zv[i].x*cv.x + zv[i].y*cv.y + zv[i].z*cv.z + zv[i].w*cv.w;
                }
            }
        }
#pragma unroll
        for (int j = 0; j < 8; j++) {
            int cl = cg + 16 * j;
            float eq = eqs[cl];
#pragma unroll
            for (int i = 0; i < 4; i++) {
                float d2 = (zr[i] - 2.f * dot[i][j]) + eq;
                if (d2 < best[i]) { best[i] = d2; bidx[i] = cc + cl; }
            }
        }
    }
    // LDS argmin reduce across the 16 lane-columns of each row
#pragma unroll
    for (int i = 0; i < 4; i++) {
        rbest[(rg + 16 * i) * 17 + cg] = best[i];
        ridx [(rg + 16 * i) * 17 + cg] = bidx[i];
    }
    __syncthreads();
    if (t < 64) {
        float b = rbest[t * 17]; int bi = ridx[t * 17];
        for (int l = 1; l < 16; l++) {
            float ob = rbest[t * 17 + l]; int oi = ridx[t * 17 + l];
            if (ob < b || (ob == b && oi < bi)) { b = ob; bi = oi; }
        }
        int c = bi & (NEMB - 1);
        int row = brow + t;
        idx_out[row] = (float)c;
        float s = 0.f;
#pragma unroll
        for (int d4 = 0; d4 < 64; d4 += 4) {
            float4 q = *reinterpret_cast<const float4*>(&cb[(size_t)c * NLAT + d4]);
            float z0 = zs[t * 68 + d4 + 0], z1 = zs[t * 68 + d4 + 1];
            float z2 = zs[t * 68 + d4 + 2], z3 = zs[t * 68 + d4 + 3];
            float dx = q.x - z0, dy = q.y - z1, dz = q.z - z2, dw = q.w - z3;
            s += dx*dx + dy*dy + dz*dz + dw*dw;
            *reinterpret_cast<float4*>(&zq_out[(size_t)row * NLAT + d4]) = q;
        }
        lred[t] = s;
    }
    __syncthreads();
    if (t == 0) {
        float s = 0.f;
        for (int q = 0; q < 64; q++) s += lred[q];
        partials[blockIdx.x] = s;
    }
}

// ---------------- loss: deterministic fixed-order sum ----------------
__global__ void loss_kernel(const float* __restrict__ partials, float* __restrict__ out_loss) {
    if (threadIdx.x == 0 && blockIdx.x == 0) {
        float s = 0.f;
        for (int i = 0; i < 512; i++) s += partials[i];
        *out_loss = (1.f + BETA) * s / (float)((size_t)NB * NLAT);
    }
}

// ---------------- fused decoder: x_recon = relu(z_q@W1+b1)@W2 + b2 ----------------
// Reads z_q (f32) from the output region. grid: 512 row-blocks x 4 col-blocks.
__global__ __launch_bounds__(256)
void dec_kernel(const float* __restrict__ out_base,
                const float* __restrict__ w1, const float* __restrict__ b1,
                const float* __restrict__ w2, const float* __restrict__ b2,
                float* __restrict__ xr) {
    const float* zq_in = out_base + ZQ_OFF;

    __shared__ __align__(16) float zqs[64 * 68];
    __shared__ __align__(16) float w1s[64 * 68];
    __shared__ __align__(16) float hds[64 * 68];
    const int t = threadIdx.x;
    const int rg = t >> 4, cg = t & 15;
    const int rb = blockIdx.x >> 2, cbk = blockIdx.x & 3;
    const int brow = rb * 64, cbase = cbk * 256;

#pragma unroll
    for (int jj = 0; jj < 4; jj++) {                      // stage z_q tile [64][64]
        int e4 = t + 256 * jj;
        int r = e4 >> 4, c4 = (e4 & 15) * 4;
        *reinterpret_cast<float4*>(&zqs[r * 68 + c4]) =
            *reinterpret_cast<const float4*>(&zq_in[(size_t)(brow + r) * NLAT + c4]);
    }

    float4 xacc[4][4];
#pragma unroll
    for (int i = 0; i < 4; i++)
#pragma unroll
        for (int g = 0; g < 4; g++) xacc[i][g] = make_float4(0.f, 0.f, 0.f, 0.f);

    for (int hc = 0; hc < NHID; hc += 64) {
        __syncthreads();
#pragma unroll
        for (int jj = 0; jj < 4; jj++) {                  // stage dec_w1 tile [64][64]
            int e4 = t + 256 * jj;
            int r = e4 >> 4, c4 = (e4 & 15) * 4;
            *reinterpret_cast<float4*>(&w1s[r * 68 + c4]) =
                *reinterpret_cast<const float4*>(&w1[(size_t)r * NHID + hc + c4]);
        }
        __syncthreads();
        float4 ha[4];
#pragma unroll
        for (int i = 0; i < 4; i++) ha[i] = make_float4(0.f, 0.f, 0.f, 0.f);
#pragma unroll 8
        for (int d = 0; d < 64; d++) {
            float a0 = zqs[(rg +  0) * 68 + d];
            float a1 = zqs[(rg + 16) * 68 + d];
            float a2 = zqs[(rg + 32) * 68 + d];
            float a3 = zqs[(rg + 48) * 68 + d];
            float4 w4 = *reinterpret_cast<float4*>(&w1s[d * 68 + cg * 4]);
            fma4(ha[0], a0, w4); fma4(ha[1], a1, w4);
            fma4(ha[2], a2, w4); fma4(ha[3], a3, w4);
        }
        float4 bv = *reinterpret_cast<const float4*>(&b1[hc + cg * 4]);
#pragma unroll
        for (int i = 0; i < 4; i++) {
            float4 h;
            h.x = fmaxf(ha[i].x + bv.x, 0.f);
            h.y = fmaxf(ha[i].y + bv.y, 0.f);
            h.z = fmaxf(ha[i].z + bv.z, 0.f);
            h.w = fmaxf(ha[i].w + bv.w, 0.f);
            *reinterpret_cast<float4*>(&hds[(rg + 16 * i) * 68 + cg * 4]) = h;
        }
        __syncthreads();
#pragma unroll 2
        for (int k = 0; k < 64; k++) {
            float h0 = hds[(rg +  0) * 68 + k];
            float h1 = hds[(rg + 16) * 68 + k];
            float h2 = hds[(rg + 32) * 68 + k];
            float h3 = hds[(rg + 48) * 68 + k];
            const float* wr = &w2[(size_t)(hc + k) * NIN + cbase + cg * 16];
            float4 wa = *reinterpret_cast<const float4*>(wr + 0);
            float4 wb = *reinterpret_cast<const float4*>(wr + 4);
            float4 wc = *reinterpret_cast<const float4*>(wr + 8);
            float4 wd = *reinterpret_cast<const float4*>(wr + 12);
            fma4(xacc[0][0], h0, wa); fma4(xacc[0][1], h0, wb); fma4(xacc[0][2], h0, wc); fma4(xacc[0][3], h0, wd);
            fma4(xacc[1][0], h1, wa); fma4(xacc[1][1], h1, wb); fma4(xacc[1][2], h1, wc); fma4(xacc[1][3], h1, wd);
            fma4(xacc[2][0], h2, wa); fma4(xacc[2][1], h2, wb); fma4(xacc[2][2], h2, wc); fma4(xacc[2][3], h2, wd);
            fma4(xacc[3][0], h3, wa); fma4(xacc[3][1], h3, wb); fma4(xacc[3][2], h3, wc); fma4(xacc[3][3], h3, wd);
        }
    }
    const float* bp = &b2[cbase + cg * 16];
    float4 bb[4];
#pragma unroll
    for (int g = 0; g < 4; g++) bb[g] = *reinterpret_cast<const float4*>(bp + 4 * g);
#pragma unroll
    for (int i = 0; i < 4; i++) {
        int row = brow + rg + 16 * i;
        float* orow = &xr[(size_t)row * NIN + cbase + cg * 16];
#pragma unroll
        for (int g = 0; g < 4; g++) {
            float4 v = xacc[i][g];
            v.x += bb[g].x; v.y += bb[g].y; v.z += bb[g].z; v.w += bb[g].w;
            *reinterpret_cast<float4*>(orow + 4 * g) = v;
        }
    }
}

extern "C" void kernel_launch(void* const* d_in, const int* in_sizes, int n_in,
                              void* d_out, int out_size, void* d_ws, size_t ws_size,
                              hipStream_t stream) {
    (void)in_sizes; (void)n_in; (void)out_size; (void)ws_size;
    const float* x   = (const float*)d_in[0];
    const float* ew1 = (const float*)d_in[1];
    const float* eb1 = (const float*)d_in[2];
    const float* ew2 = (const float*)d_in[3];
    const float* eb2 = (const float*)d_in[4];
    const float* cb  = (const float*)d_in[5];
    const float* dw1 = (const float*)d_in[6];
    const float* db1 = (const float*)d_in[7];
    const float* dw2 = (const float*)d_in[8];
    const float* db2 = (const float*)d_in[9];

    float* out  = (float*)d_out;
    float* part = (float*)d_ws + PART_WS;

    encvq_kernel<<<NB / 64, 256, 0, stream>>>(x, ew1, eb1, ew2, eb2, cb, out, part);
    loss_kernel<<<1, 64, 0, stream>>>(part, out + LOSS_OFF);
    dec_kernel<<<(NB / 64) * 4, 256, 0, stream>>>(out, dw1, db1, dw2, db2, out + XR_OFF);
}

// Round 8
// 3278.595 us; speedup vs baseline: 2.1355x; 2.1355x over previous
//
#include <hip/hip_runtime.h>
#include <hip/hip_bf16.h>

#define NB    32768
#define NIN   1024
#define NHID  2048
#define NLAT  64
#define NEMB  4096
#define BETA  0.25f

#define FLTMAX 3.402823466e+38f

// ---- output layout (FLOAT32 elements) ----
#define XR_OFF   0
#define ZE_OFF   33554432
#define ZQ_OFF   35651584
#define IDX_OFF  37748736
#define LOSS_OFF 37781504

// ---- ws layout (bytes) ----
// [0,2048)        : 512 f32 loss partials
// [4096, 266240)  : w1t bf16 [2048 h][64 l]   (dec_w1 transposed)
// [266240, 4460544): w2t bf16 [1024 c][2048 k] (dec_w2 transposed)
#define PART_WS_F   0
#define W1T_WS_B    4096
#define W2T_WS_B    266240

typedef short v8s __attribute__((ext_vector_type(8)));
typedef float v4f __attribute__((ext_vector_type(4)));

static __device__ __forceinline__ unsigned short f2bf(float f) {
    union { __hip_bfloat16 h; unsigned short u; } v;
    v.h = __float2bfloat16(f);
    return v.u;
}

static __device__ __forceinline__ void fma4(float4& acc, float s, const float4& wv) {
    acc.x += s * wv.x; acc.y += s * wv.y; acc.z += s * wv.z; acc.w += s * wv.w;
}

// ---------------- prep: transpose+convert decoder weights to bf16 ----------------
__global__ void prep_w1t(const float* __restrict__ dw1, unsigned short* __restrict__ w1t) {
    int idx = blockIdx.x * 256 + threadIdx.x;        // 131072 = 64*2048
    int l = idx >> 11, h = idx & 2047;
    w1t[h * 64 + l] = f2bf(dw1[l * 2048 + h]);
}
__global__ void prep_w2t(const float* __restrict__ dw2, unsigned short* __restrict__ w2t) {
    int idx = blockIdx.x * 256 + threadIdx.x;        // 2097152 = 2048*1024
    int k = idx >> 10, c = idx & 1023;
    w2t[(size_t)c * 2048 + k] = f2bf(dw2[(size_t)k * 1024 + c]);
}

// ---------------- fused encoder + VQ (fp32, exact indices) ----------------
// 256 threads, 64 rows/block. thread (rg=t>>4, cg=t&15): rows rg+16i, cols cg*4..+3
__global__ __launch_bounds__(256)
void encvq_kernel(const float* __restrict__ x,  const float* __restrict__ w1,
                  const float* __restrict__ b1, const float* __restrict__ w2,
                  const float* __restrict__ b2, const float* __restrict__ cb,
                  float* __restrict__ out, float* __restrict__ partials) {
    float* ze_out  = out + ZE_OFF;
    float* zq_out  = out + ZQ_OFF;
    float* idx_out = out + IDX_OFF;

    __shared__ __align__(16) float smem[3 * 64 * 72];   // 54 KB
    float* xs = smem;
    float* wt = smem + 64 * 72;
    float* hs = smem + 2 * 64 * 72;
    float* zs = smem;                 // vq phase: aliases xs
    float* cbs = smem + 64 * 72;      // vq phase: [128*72] aliases wt+hs exactly
    __shared__ float zsq[64];
    __shared__ float lred[64];
    __shared__ float eqs[128];
    __shared__ float rbest[64 * 17];
    __shared__ int   ridx[64 * 17];

    const int t = threadIdx.x;
    const int rg = t >> 4, cg = t & 15;
    const int brow = blockIdx.x * 64;

    // ---------------- phase 1: encoder ----------------
    float4 zacc[4];
#pragma unroll
    for (int i = 0; i < 4; i++) zacc[i] = make_float4(0.f, 0.f, 0.f, 0.f);

    for (int jc = 0; jc < NHID; jc += 64) {
        float4 hacc[4];
#pragma unroll
        for (int i = 0; i < 4; i++) hacc[i] = make_float4(0.f, 0.f, 0.f, 0.f);

        for (int kc = 0; kc < NIN; kc += 64) {
            __syncthreads();
#pragma unroll
            for (int jj = 0; jj < 4; jj++) {              // stage x tile [64][64]
                int e4 = t + 256 * jj;
                int r = e4 >> 4, c4 = (e4 & 15) * 4;
                *reinterpret_cast<float4*>(&xs[r * 72 + c4]) =
                    *reinterpret_cast<const float4*>(&x[(size_t)(brow + r) * NIN + kc + c4]);
            }
#pragma unroll
            for (int jj = 0; jj < 4; jj++) {              // stage w1 tile [64][64]
                int e4 = t + 256 * jj;
                int r = e4 >> 4, c4 = (e4 & 15) * 4;
                *reinterpret_cast<float4*>(&wt[r * 72 + c4]) =
                    *reinterpret_cast<const float4*>(&w1[(size_t)(kc + r) * NHID + jc + c4]);
            }
            __syncthreads();
#pragma unroll 4
            for (int k4 = 0; k4 < 64; k4 += 4) {
                float4 av[4], wv[4];
#pragma unroll
                for (int i = 0; i < 4; i++)
                    av[i] = *reinterpret_cast<float4*>(&xs[(rg + 16 * i) * 72 + k4]);
#pragma unroll
                for (int j = 0; j < 4; j++)
                    wv[j] = *reinterpret_cast<float4*>(&wt[(k4 + j) * 72 + cg * 4]);
#pragma unroll
                for (int i = 0; i < 4; i++) {
                    fma4(hacc[i], av[i].x, wv[0]); fma4(hacc[i], av[i].y, wv[1]);
                    fma4(hacc[i], av[i].z, wv[2]); fma4(hacc[i], av[i].w, wv[3]);
                }
            }
        }
        float4 bv = *reinterpret_cast<const float4*>(&b1[jc + cg * 4]);
#pragma unroll
        for (int i = 0; i < 4; i++) {
            float4 h;
            h.x = fmaxf(hacc[i].x + bv.x, 0.f);
            h.y = fmaxf(hacc[i].y + bv.y, 0.f);
            h.z = fmaxf(hacc[i].z + bv.z, 0.f);
            h.w = fmaxf(hacc[i].w + bv.w, 0.f);
            *reinterpret_cast<float4*>(&hs[(rg + 16 * i) * 72 + cg * 4]) = h;
        }
        __syncthreads();
#pragma unroll
        for (int jj = 0; jj < 4; jj++) {                  // stage w2 tile [64][64]
            int e4 = t + 256 * jj;
            int r = e4 >> 4, c4 = (e4 & 15) * 4;
            *reinterpret_cast<float4*>(&wt[r * 72 + c4]) =
                *reinterpret_cast<const float4*>(&w2[(size_t)(jc + r) * NLAT + c4]);
        }
        __syncthreads();
#pragma unroll 2
        for (int k4 = 0; k4 < 64; k4 += 4) {
            float4 av[4], wv[4];
#pragma unroll
            for (int i = 0; i < 4; i++)
                av[i] = *reinterpret_cast<float4*>(&hs[(rg + 16 * i) * 72 + k4]);
#pragma unroll
            for (int j = 0; j < 4; j++)
                wv[j] = *reinterpret_cast<float4*>(&wt[(k4 + j) * 72 + cg * 4]);
#pragma unroll
            for (int i = 0; i < 4; i++) {
                fma4(zacc[i], av[i].x, wv[0]); fma4(zacc[i], av[i].y, wv[1]);
                fma4(zacc[i], av[i].z, wv[2]); fma4(zacc[i], av[i].w, wv[3]);
            }
        }
    }
    __syncthreads();   // protect zs (= xs alias) overwrite
    float4 b2v = *reinterpret_cast<const float4*>(&b2[cg * 4]);
#pragma unroll
    for (int i = 0; i < 4; i++) {
        int row = brow + rg + 16 * i;
        float4 z = zacc[i];
        z.x += b2v.x; z.y += b2v.y; z.z += b2v.z; z.w += b2v.w;
        *reinterpret_cast<float4*>(&zs[(rg + 16 * i) * 72 + cg * 4]) = z;
        *reinterpret_cast<float4*>(&ze_out[(size_t)row * NLAT + cg * 4]) = z;
    }
    __syncthreads();

    // ---------------- phase 2: VQ ----------------
    if (t < 64) {
        float s = 0.f;
#pragma unroll 16
        for (int d = 0; d < 64; d++) { float v = zs[t * 72 + d]; s += v * v; }
        zsq[t] = s;
    }
    __syncthreads();
    float zr[4];
#pragma unroll
    for (int i = 0; i < 4; i++) zr[i] = zsq[rg + 16 * i];

    float best[4]; int bidx[4];
#pragma unroll
    for (int i = 0; i < 4; i++) { best[i] = FLTMAX; bidx[i] = 0; }

    for (int cc = 0; cc < NEMB; cc += 128) {
        __syncthreads();
#pragma unroll
        for (int jj = 0; jj < 8; jj++) {                  // stage codebook chunk [128][64]
            int e4 = t + 256 * jj;
            int r = e4 >> 4, c4 = (e4 & 15) * 4;
            *reinterpret_cast<float4*>(&cbs[r * 72 + c4]) =
                *reinterpret_cast<const float4*>(&cb[(size_t)(cc + r) * NLAT + c4]);
        }
        __syncthreads();
        if (t < 128) {                                    // in-LDS codebook norms
            float s = 0.f;
#pragma unroll 16
            for (int d = 0; d < 64; d++) { float v = cbs[t * 72 + d]; s += v * v; }
            eqs[t] = s;
        }
        __syncthreads();
        float dot[4][8];
#pragma unroll
        for (int i = 0; i < 4; i++)
#pragma unroll
            for (int j = 0; j < 8; j++) dot[i][j] = 0.f;
#pragma unroll 4
        for (int d4 = 0; d4 < 64; d4 += 4) {
            float4 zv[4];
#pragma unroll
            for (int i = 0; i < 4; i++)
                zv[i] = *reinterpret_cast<float4*>(&zs[(rg + 16 * i) * 72 + d4]);
#pragma unroll
            for (int j = 0; j < 8; j++) {
                float4 cv = *reinterpret_cast<float4*>(&cbs[(cg + 16 * j) * 72 + d4]);
#pragma unroll
                for (int i = 0; i < 4; i++) {
                    dot[i][j] += zv[i].x*cv.x + zv[i].y*cv.y + zv[i].z*cv.z + zv[i].w*cv.w;
                }
            }
        }
#pragma unroll
        for (int j = 0; j < 8; j++) {
            int cl = cg + 16 * j;
            float eq = eqs[cl];
#pragma unroll
            for (int i = 0; i < 4; i++) {
                float d2 = (zr[i] - 2.f * dot[i][j]) + eq;
                if (d2 < best[i]) { best[i] = d2; bidx[i] = cc + cl; }
            }
        }
    }
#pragma unroll
    for (int i = 0; i < 4; i++) {
        rbest[(rg + 16 * i) * 17 + cg] = best[i];
        ridx [(rg + 16 * i) * 17 + cg] = bidx[i];
    }
    __syncthreads();
    if (t < 64) {
        float b = rbest[t * 17]; int bi = ridx[t * 17];
        for (int l = 1; l < 16; l++) {
            float ob = rbest[t * 17 + l]; int oi = ridx[t * 17 + l];
            if (ob < b || (ob == b && oi < bi)) { b = ob; bi = oi; }
        }
        int c = bi & (NEMB - 1);
        int row = brow + t;
        idx_out[row] = (float)c;
        float s = 0.f;
#pragma unroll
        for (int d4 = 0; d4 < 64; d4 += 4) {
            float4 q = *reinterpret_cast<const float4*>(&cb[(size_t)c * NLAT + d4]);
            float z0 = zs[t * 72 + d4 + 0], z1 = zs[t * 72 + d4 + 1];
            float z2 = zs[t * 72 + d4 + 2], z3 = zs[t * 72 + d4 + 3];
            float dx = q.x - z0, dy = q.y - z1, dz = q.z - z2, dw = q.w - z3;
            s += dx*dx + dy*dy + dz*dz + dw*dw;
            *reinterpret_cast<float4*>(&zq_out[(size_t)row * NLAT + d4]) = q;
        }
        lred[t] = s;
    }
    __syncthreads();
    if (t == 0) {
        float s = 0.f;
        for (int q = 0; q < 64; q++) s += lred[q];
        partials[blockIdx.x] = s;
    }
}

// ---------------- loss ----------------
__global__ void loss_kernel(const float* __restrict__ partials, float* __restrict__ out_loss) {
    if (threadIdx.x == 0 && blockIdx.x == 0) {
        float s = 0.f;
        for (int i = 0; i < 512; i++) s += partials[i];
        *out_loss = (1.f + BETA) * s / (float)((size_t)NB * NLAT);
    }
}

// ---------------- MFMA decoder ----------------
// block: 256 threads = 4 waves; output tile 64 rows x 256 cols.
// chunk loop over hidden (64/step): phase A hd=relu(zq@w1+b1) via MFMA -> LDS bf16;
// phase B xacc += hd @ w2 via MFMA.  Fragment maps (16x16x32):
//   A: lane l holds A[l&15][8*(l>>4)+e];  B: lane l holds B[8*(l>>4)+e][l&15];
//   D: lane l holds D[4*(l>>4)+r][l&15]  (m89-verified C/D).
__global__ __launch_bounds__(256)
void dec_kernel(const float* __restrict__ out_base,
                const unsigned short* __restrict__ w1t,   // [2048 h][64 l] bf16
                const unsigned short* __restrict__ w2t,   // [1024 c][2048 k] bf16
                const float* __restrict__ b1, const float* __restrict__ b2,
                float* __restrict__ xr) {
    const float* zq_in = out_base + ZQ_OFF;

    __shared__ __align__(16) unsigned short zqb[64 * 72];   // [row][latent]
    __shared__ __align__(16) unsigned short w1b[64 * 72];   // [hid col][latent]
    __shared__ __align__(16) unsigned short hdb[64 * 72];   // [row][hid k]
    __shared__ __align__(16) unsigned short w2b[256 * 72];  // [out col][hid k]

    const int t = threadIdx.x;
    const int w = t >> 6, lane = t & 63, lo = lane & 15, hi = lane >> 4;
    const int rb = blockIdx.x >> 2, cbk = blockIdx.x & 3;
    const int brow = rb * 64, cbase = cbk * 256;

    // stage zq -> bf16 LDS (once)
    {
        int row = t & 63, m = t >> 6;                     // 16 f32 per thread
        const float* src = &zq_in[(size_t)(brow + row) * NLAT + m * 16];
        unsigned int us[8];
#pragma unroll
        for (int j = 0; j < 4; j++) {
            float4 v = *reinterpret_cast<const float4*>(src + 4 * j);
            us[2*j]   = (unsigned int)f2bf(v.x) | ((unsigned int)f2bf(v.y) << 16);
            us[2*j+1] = (unsigned int)f2bf(v.z) | ((unsigned int)f2bf(v.w) << 16);
        }
        uint4 p0 = make_uint4(us[0], us[1], us[2], us[3]);
        uint4 p1 = make_uint4(us[4], us[5], us[6], us[7]);
        *reinterpret_cast<uint4*>(&zqb[row * 72 + m * 16 + 0]) = p0;
        *reinterpret_cast<uint4*>(&zqb[row * 72 + m * 16 + 8]) = p1;
    }

    v4f facc[4][4];
#pragma unroll
    for (int i = 0; i < 4; i++)
#pragma unroll
        for (int j = 0; j < 4; j++) facc[i][j] = (v4f){0.f, 0.f, 0.f, 0.f};

    for (int hc = 0; hc < NHID; hc += 64) {
        __syncthreads();                                   // prev-iter reads done
        // stage w1b: [64 c][64 l] bf16 — 2 x 16B per thread
        {
            int cl = t & 63, mm = (t >> 6) * 2;
#pragma unroll
            for (int j = 0; j < 2; j++) {
                uint4 v = *reinterpret_cast<const uint4*>(&w1t[(size_t)(hc + cl) * 64 + (mm + j) * 8]);
                *reinterpret_cast<uint4*>(&w1b[cl * 72 + (mm + j) * 8]) = v;
            }
        }
        // stage w2b: [256 c][64 k] bf16 — one row (128B) per thread
        {
            const unsigned short* src = &w2t[(size_t)(cbase + t) * 2048 + hc];
#pragma unroll
            for (int j = 0; j < 8; j++) {
                uint4 v = *reinterpret_cast<const uint4*>(src + j * 8);
                *reinterpret_cast<uint4*>(&w2b[t * 72 + j * 8]) = v;
            }
        }
        __syncthreads();

        // ---- phase A: hd[64][64] = relu(zq @ w1 + b1); wave w does rows 16w..16w+15
        v8s a0 = *reinterpret_cast<const v8s*>(&zqb[(16 * w + lo) * 72 +  0 + hi * 8]);
        v8s a1 = *reinterpret_cast<const v8s*>(&zqb[(16 * w + lo) * 72 + 32 + hi * 8]);
#pragma unroll
        for (int ct = 0; ct < 4; ct++) {
            v8s bb0 = *reinterpret_cast<const v8s*>(&w1b[(16 * ct + lo) * 72 +  0 + hi * 8]);
            v8s bb1 = *reinterpret_cast<const v8s*>(&w1b[(16 * ct + lo) * 72 + 32 + hi * 8]);
            v4f acc = (v4f){0.f, 0.f, 0.f, 0.f};
            acc = __builtin_amdgcn_mfma_f32_16x16x32_bf16(a0, bb0, acc, 0, 0, 0);
            acc = __builtin_amdgcn_mfma_f32_16x16x32_bf16(a1, bb1, acc, 0, 0, 0);
            float bias = b1[hc + 16 * ct + lo];
#pragma unroll
            for (int r = 0; r < 4; r++) {
                float hv = fmaxf(acc[r] + bias, 0.f);
                hdb[(16 * w + 4 * hi + r) * 72 + 16 * ct + lo] = f2bf(hv);
            }
        }
        __syncthreads();

        // ---- phase B: facc += hd @ w2 ; wave w does cols 64w..64w+63
#pragma unroll
        for (int kk = 0; kk < 2; kk++) {
            v8s af[4];
#pragma unroll
            for (int rt = 0; rt < 4; rt++)
                af[rt] = *reinterpret_cast<const v8s*>(&hdb[(16 * rt + lo) * 72 + kk * 32 + hi * 8]);
#pragma unroll
            for (int ctl = 0; ctl < 4; ctl++) {
                v8s bf_ = *reinterpret_cast<const v8s*>(&w2b[(64 * w + 16 * ctl + lo) * 72 + kk * 32 + hi * 8]);
#pragma unroll
                for (int rt = 0; rt < 4; rt++)
                    facc[rt][ctl] = __builtin_amdgcn_mfma_f32_16x16x32_bf16(af[rt], bf_, facc[rt][ctl], 0, 0, 0);
            }
        }
    }

    // epilogue: bias + store f32
#pragma unroll
    for (int ctl = 0; ctl < 4; ctl++) {
        int col = cbase + 64 * w + 16 * ctl + lo;
        float bias = b2[col];
#pragma unroll
        for (int rt = 0; rt < 4; rt++) {
#pragma unroll
            for (int r = 0; r < 4; r++) {
                int row = brow + 16 * rt + 4 * hi + r;
                xr[(size_t)row * NIN + col] = facc[rt][ctl][r] + bias;
            }
        }
    }
}

extern "C" void kernel_launch(void* const* d_in, const int* in_sizes, int n_in,
                              void* d_out, int out_size, void* d_ws, size_t ws_size,
                              hipStream_t stream) {
    (void)in_sizes; (void)n_in; (void)out_size; (void)ws_size;
    const float* x   = (const float*)d_in[0];
    const float* ew1 = (const float*)d_in[1];
    const float* eb1 = (const float*)d_in[2];
    const float* ew2 = (const float*)d_in[3];
    const float* eb2 = (const float*)d_in[4];
    const float* cb  = (const float*)d_in[5];
    const float* dw1 = (const float*)d_in[6];
    const float* db1 = (const float*)d_in[7];
    const float* dw2 = (const float*)d_in[8];
    const float* db2 = (const float*)d_in[9];

    float* out  = (float*)d_out;
    float* part = (float*)d_ws + PART_WS_F;
    unsigned short* w1t = (unsigned short*)((char*)d_ws + W1T_WS_B);
    unsigned short* w2t = (unsigned short*)((char*)d_ws + W2T_WS_B);

    prep_w1t<<<512, 256, 0, stream>>>(dw1, w1t);
    prep_w2t<<<8192, 256, 0, stream>>>(dw2, w2t);
    encvq_kernel<<<NB / 64, 256, 0, stream>>>(x, ew1, eb1, ew2, eb2, cb, out, part);
    loss_kernel<<<1, 64, 0, stream>>>(part, out + LOSS_OFF);
    dec_kernel<<<(NB / 64) * 4, 256, 0, stream>>>(out, w1t, w2t, db1, db2, out + XR_OFF);
}

// Round 10
// 2900.150 us; speedup vs baseline: 2.4141x; 1.1305x over previous
//
#include <hip/hip_runtime.h>
#include <hip/hip_bf16.h>

#define NB    32768
#define NIN   1024
#define NHID  2048
#define NLAT  64
#define NEMB  4096
#define BETA  0.25f

#define FLTMAX 3.402823466e+38f

// ---- output layout (FLOAT32 elements) ----
#define XR_OFF   0
#define ZE_OFF   33554432
#define ZQ_OFF   35651584
#define IDX_OFF  37748736
#define LOSS_OFF 37781504

// ---- ws layout (bytes) ----
#define PART_WS_F   0          // 256 f32 loss partials
#define W1T_WS_B    4096
#define W2T_WS_B    266240

typedef short v8s __attribute__((ext_vector_type(8)));
typedef float v4f __attribute__((ext_vector_type(4)));

static __device__ __forceinline__ unsigned short f2bf(float f) {
    union { __hip_bfloat16 h; unsigned short u; } v;
    v.h = __float2bfloat16(f);
    return v.u;
}

static __device__ __forceinline__ void fma4(float4& acc, float s, const float4& wv) {
    acc.x += s * wv.x; acc.y += s * wv.y; acc.z += s * wv.z; acc.w += s * wv.w;
}

// ---------------- prep: transpose+convert decoder weights to bf16 ----------------
__global__ void prep_w1t(const float* __restrict__ dw1, unsigned short* __restrict__ w1t) {
    int idx = blockIdx.x * 256 + threadIdx.x;
    int l = idx >> 11, h = idx & 2047;
    w1t[h * 64 + l] = f2bf(dw1[l * 2048 + h]);
}
__global__ void prep_w2t(const float* __restrict__ dw2, unsigned short* __restrict__ w2t) {
    int idx = blockIdx.x * 256 + threadIdx.x;
    int k = idx >> 10, c = idx & 1023;
    w2t[(size_t)c * 2048 + k] = f2bf(dw2[(size_t)k * 1024 + c]);
}

// ---------------- fused encoder + VQ (fp32, exact indices) ----------------
// 512 threads, 128 rows/block. rg=t>>5 (0..15): rows rg+16i (i 0..7);
// cg=t&31 (0..31): GEMM1 cols cg*8..+7 of the 256-wide jc chunk.
__global__ __launch_bounds__(512)
void encvq_kernel(const float* __restrict__ x,  const float* __restrict__ w1,
                  const float* __restrict__ b1, const float* __restrict__ w2,
                  const float* __restrict__ b2, const float* __restrict__ cb,
                  float* __restrict__ out, float* __restrict__ partials) {
    float* ze_out  = out + ZE_OFF;
    float* zq_out  = out + ZQ_OFF;
    float* idx_out = out + IDX_OFF;

    __shared__ __align__(16) float smem[17408];   // 69.6 KB
    float* xs  = smem;            // [128][36]
    float* wt  = smem + 4608;     // [32][288] (padded/swizzled)
    float* hs  = smem;            // [128][36] (alias xs)
    float* w2s = smem + 4608;     // [32][68]  (alias wt)
    float* zs  = smem;            // [128][68]
    float* cbs = smem + 8704;     // [128][68]
    float* rbestf = smem + 8704;  // [128][33] (alias cbs, written AFTER barrier)
    int*   ridxi  = (int*)(smem + 12928); // [128][33]
    __shared__ float zsq[128];
    __shared__ float eqs[128];
    __shared__ float lred[128];

    const int t = threadIdx.x;
    const int rg = t >> 5, cg = t & 31;
    const int brow = blockIdx.x * 128;
    const int woff = cg * 8 + (cg >> 2) * 4;     // swizzled wt column offset

    // ---------------- phase 1: encoder ----------------
    float2 zacc[8];
#pragma unroll
    for (int i = 0; i < 8; i++) zacc[i] = make_float2(0.f, 0.f);

    for (int jc = 0; jc < NHID; jc += 256) {
        float4 hacc[8][2];
#pragma unroll
        for (int i = 0; i < 8; i++) {
            hacc[i][0] = make_float4(0.f, 0.f, 0.f, 0.f);
            hacc[i][1] = make_float4(0.f, 0.f, 0.f, 0.f);
        }

        for (int kc = 0; kc < NIN; kc += 32) {
            __syncthreads();
            // stage xs [128 rows][32 k] : 1024 float4, 2/thread
#pragma unroll
            for (int jj = 0; jj < 2; jj++) {
                int id = t + 512 * jj;
                int r = id >> 3, c4 = (id & 7) * 4;
                *reinterpret_cast<float4*>(&xs[r * 36 + c4]) =
                    *reinterpret_cast<const float4*>(&x[(size_t)(brow + r) * NIN + kc + c4]);
            }
            // stage wt [32 k][256 cols] swizzled : 2048 float4, 4/thread
#pragma unroll
            for (int jj = 0; jj < 4; jj++) {
                int id = t + 512 * jj;
                int r = id >> 6, c4 = (id & 63) * 4;
                *reinterpret_cast<float4*>(&wt[r * 288 + c4 + ((c4 >> 5) << 2)]) =
                    *reinterpret_cast<const float4*>(&w1[(size_t)(kc + r) * NHID + jc + c4]);
            }
            __syncthreads();
            for (int k4 = 0; k4 < 32; k4 += 4) {
                float4 av[8];
#pragma unroll
                for (int i = 0; i < 8; i++)
                    av[i] = *reinterpret_cast<float4*>(&xs[(rg + 16 * i) * 36 + k4]);
#pragma unroll
                for (int kk = 0; kk < 4; kk++) {
                    float4 wv0 = *reinterpret_cast<float4*>(&wt[(k4 + kk) * 288 + woff]);
                    float4 wv1 = *reinterpret_cast<float4*>(&wt[(k4 + kk) * 288 + woff + 4]);
#pragma unroll
                    for (int i = 0; i < 8; i++) {
                        float a = (kk == 0) ? av[i].x : (kk == 1) ? av[i].y : (kk == 2) ? av[i].z : av[i].w;
                        fma4(hacc[i][0], a, wv0);
                        fma4(hacc[i][1], a, wv1);
                    }
                }
            }
        }

        // GEMM2 over 8 sub-chunks of 32 hidden cols
        for (int cs = 0; cs < 8; cs++) {
            __syncthreads();   // prev reads of hs/w2s (and GEMM1 xs/wt) done
            if ((cg >> 2) == cs) {                          // owners write h chunk
                float4 b1a = *reinterpret_cast<const float4*>(&b1[jc + cg * 8]);
                float4 b1b = *reinterpret_cast<const float4*>(&b1[jc + cg * 8 + 4]);
#pragma unroll
                for (int i = 0; i < 8; i++) {
                    float4 h0, h1;
                    h0.x = fmaxf(hacc[i][0].x + b1a.x, 0.f);
                    h0.y = fmaxf(hacc[i][0].y + b1a.y, 0.f);
                    h0.z = fmaxf(hacc[i][0].z + b1a.z, 0.f);
                    h0.w = fmaxf(hacc[i][0].w + b1a.w, 0.f);
                    h1.x = fmaxf(hacc[i][1].x + b1b.x, 0.f);
                    h1.y = fmaxf(hacc[i][1].y + b1b.y, 0.f);
                    h1.z = fmaxf(hacc[i][1].z + b1b.z, 0.f);
                    h1.w = fmaxf(hacc[i][1].w + b1b.w, 0.f);
                    *reinterpret_cast<float4*>(&hs[(rg + 16 * i) * 36 + (cg & 3) * 8]) = h0;
                    *reinterpret_cast<float4*>(&hs[(rg + 16 * i) * 36 + (cg & 3) * 8 + 4]) = h1;
                }
            }
            // stage w2s [32][64] : 512 float4, 1/thread
            {
                int r = t >> 4, c4 = (t & 15) * 4;
                *reinterpret_cast<float4*>(&w2s[r * 68 + c4]) =
                    *reinterpret_cast<const float4*>(&w2[(size_t)(jc + 32 * cs + r) * NLAT + c4]);
            }
            __syncthreads();
#pragma unroll 4
            for (int k = 0; k < 32; k++) {
                float2 wv = *reinterpret_cast<float2*>(&w2s[k * 68 + cg * 2]);
#pragma unroll
                for (int i = 0; i < 8; i++) {
                    float hv = hs[(rg + 16 * i) * 36 + k];
                    zacc[i].x += hv * wv.x;
                    zacc[i].y += hv * wv.y;
                }
            }
        }
    }

    // finalize z: bias, write zs + ze_out
    __syncthreads();   // all GEMM2 reads done before zs overwrites xs/wt region
    {
        float2 b2v = *reinterpret_cast<const float2*>(&b2[cg * 2]);
#pragma unroll
        for (int i = 0; i < 8; i++) {
            int row = brow + rg + 16 * i;
            float2 z = make_float2(zacc[i].x + b2v.x, zacc[i].y + b2v.y);
            *reinterpret_cast<float2*>(&zs[(rg + 16 * i) * 68 + cg * 2]) = z;
            *reinterpret_cast<float2*>(&ze_out[(size_t)row * NLAT + cg * 2]) = z;
        }
    }
    __syncthreads();

    // ---------------- phase 2: VQ ----------------
    if (t < 128) {
        float s = 0.f;
#pragma unroll 16
        for (int d = 0; d < 64; d++) { float v = zs[t * 68 + d]; s += v * v; }
        zsq[t] = s;
    }
    __syncthreads();
    float zr[8];
#pragma unroll
    for (int i = 0; i < 8; i++) zr[i] = zsq[rg + 16 * i];

    float best[8]; int bidx[8];
#pragma unroll
    for (int i = 0; i < 8; i++) { best[i] = FLTMAX; bidx[i] = 0; }

    for (int cc = 0; cc < NEMB; cc += 128) {
        __syncthreads();
#pragma unroll
        for (int jj = 0; jj < 4; jj++) {                  // stage codebook [128][64]
            int id = t + 512 * jj;
            int r = id >> 4, c4 = (id & 15) * 4;
            *reinterpret_cast<float4*>(&cbs[r * 68 + c4]) =
                *reinterpret_cast<const float4*>(&cb[(size_t)(cc + r) * NLAT + c4]);
        }
        __syncthreads();
        if (t < 128) {                                    // in-LDS codebook norms
            float s = 0.f;
#pragma unroll 16
            for (int d = 0; d < 64; d++) { float v = cbs[t * 68 + d]; s += v * v; }
            eqs[t] = s;
        }
        __syncthreads();
        float dot[8][4];
#pragma unroll
        for (int i = 0; i < 8; i++)
#pragma unroll
            for (int j = 0; j < 4; j++) dot[i][j] = 0.f;
#pragma unroll 2
        for (int d4 = 0; d4 < 64; d4 += 4) {
            float4 zv[8];
#pragma unroll
            for (int i = 0; i < 8; i++)
                zv[i] = *reinterpret_cast<float4*>(&zs[(rg + 16 * i) * 68 + d4]);
#pragma unroll
            for (int j = 0; j < 4; j++) {
                float4 cv = *reinterpret_cast<float4*>(&cbs[(cg + 32 * j) * 68 + d4]);
#pragma unroll
                for (int i = 0; i < 8; i++) {
                    dot[i][j] += zv[i].x*cv.x + zv[i].y*cv.y + zv[i].z*cv.z + zv[i].w*cv.w;
                }
            }
        }
#pragma unroll
        for (int j = 0; j < 4; j++) {
            int cl = cg + 32 * j;                         // ascending per thread
            float eq = eqs[cl];
#pragma unroll
            for (int i = 0; i < 8; i++) {
                float d2 = (zr[i] - 2.f * dot[i][j]) + eq;
                if (d2 < best[i]) { best[i] = d2; bidx[i] = cc + cl; }
            }
        }
    }
    // RACE FIX (R9 bug): rbestf/ridxi alias cbs — ensure ALL threads have
    // finished their last cbs dot-product reads before any thread overwrites.
    __syncthreads();
    // LDS argmin reduce across the 32 lane-columns of each row
#pragma unroll
    for (int i = 0; i < 8; i++) {
        rbestf[(rg + 16 * i) * 33 + cg] = best[i];
        ridxi [(rg + 16 * i) * 33 + cg] = bidx[i];
    }
    __syncthreads();
    if (t < 128) {
        float b = rbestf[t * 33]; int bi = ridxi[t * 33];
        for (int l = 1; l < 32; l++) {
            float ob = rbestf[t * 33 + l]; int oi = ridxi[t * 33 + l];
            if (ob < b || (ob == b && oi < bi)) { b = ob; bi = oi; }
        }
        int c = bi & (NEMB - 1);
        int row = brow + t;
        idx_out[row] = (float)c;
        float s = 0.f;
#pragma unroll
        for (int d4 = 0; d4 < 64; d4 += 4) {
            float4 q = *reinterpret_cast<const float4*>(&cb[(size_t)c * NLAT + d4]);
            float z0 = zs[t * 68 + d4 + 0], z1 = zs[t * 68 + d4 + 1];
            float z2 = zs[t * 68 + d4 + 2], z3 = zs[t * 68 + d4 + 3];
            float dx = q.x - z0, dy = q.y - z1, dz = q.z - z2, dw = q.w - z3;
            s += dx*dx + dy*dy + dz*dz + dw*dw;
            *reinterpret_cast<float4*>(&zq_out[(size_t)row * NLAT + d4]) = q;
        }
        lred[t] = s;
    }
    __syncthreads();
    if (t == 0) {
        float s = 0.f;
        for (int q = 0; q < 128; q++) s += lred[q];
        partials[blockIdx.x] = s;
    }
}

// ---------------- loss ----------------
__global__ void loss_kernel(const float* __restrict__ partials, float* __restrict__ out_loss) {
    if (threadIdx.x == 0 && blockIdx.x == 0) {
        float s = 0.f;
        for (int i = 0; i < 256; i++) s += partials[i];
        *out_loss = (1.f + BETA) * s / (float)((size_t)NB * NLAT);
    }
}

// ---------------- MFMA decoder (unchanged from R8) ----------------
__global__ __launch_bounds__(256)
void dec_kernel(const float* __restrict__ out_base,
                const unsigned short* __restrict__ w1t,
                const unsigned short* __restrict__ w2t,
                const float* __restrict__ b1, const float* __restrict__ b2,
                float* __restrict__ xr) {
    const float* zq_in = out_base + ZQ_OFF;

    __shared__ __align__(16) unsigned short zqb[64 * 72];
    __shared__ __align__(16) unsigned short w1b[64 * 72];
    __shared__ __align__(16) unsigned short hdb[64 * 72];
    __shared__ __align__(16) unsigned short w2b[256 * 72];

    const int t = threadIdx.x;
    const int w = t >> 6, lane = t & 63, lo = lane & 15, hi = lane >> 4;
    const int rb = blockIdx.x >> 2, cbk = blockIdx.x & 3;
    const int brow = rb * 64, cbase = cbk * 256;

    {
        int row = t & 63, m = t >> 6;
        const float* src = &zq_in[(size_t)(brow + row) * NLAT + m * 16];
        unsigned int us[8];
#pragma unroll
        for (int j = 0; j < 4; j++) {
            float4 v = *reinterpret_cast<const float4*>(src + 4 * j);
            us[2*j]   = (unsigned int)f2bf(v.x) | ((unsigned int)f2bf(v.y) << 16);
            us[2*j+1] = (unsigned int)f2bf(v.z) | ((unsigned int)f2bf(v.w) << 16);
        }
        uint4 p0 = make_uint4(us[0], us[1], us[2], us[3]);
        uint4 p1 = make_uint4(us[4], us[5], us[6], us[7]);
        *reinterpret_cast<uint4*>(&zqb[row * 72 + m * 16 + 0]) = p0;
        *reinterpret_cast<uint4*>(&zqb[row * 72 + m * 16 + 8]) = p1;
    }

    v4f facc[4][4];
#pragma unroll
    for (int i = 0; i < 4; i++)
#pragma unroll
        for (int j = 0; j < 4; j++) facc[i][j] = (v4f){0.f, 0.f, 0.f, 0.f};

    for (int hc = 0; hc < NHID; hc += 64) {
        __syncthreads();
        {
            int cl = t & 63, mm = (t >> 6) * 2;
#pragma unroll
            for (int j = 0; j < 2; j++) {
                uint4 v = *reinterpret_cast<const uint4*>(&w1t[(size_t)(hc + cl) * 64 + (mm + j) * 8]);
                *reinterpret_cast<uint4*>(&w1b[cl * 72 + (mm + j) * 8]) = v;
            }
        }
        {
            const unsigned short* src = &w2t[(size_t)(cbase + t) * 2048 + hc];
#pragma unroll
            for (int j = 0; j < 8; j++) {
                uint4 v = *reinterpret_cast<const uint4*>(src + j * 8);
                *reinterpret_cast<uint4*>(&w2b[t * 72 + j * 8]) = v;
            }
        }
        __syncthreads();

        v8s a0 = *reinterpret_cast<const v8s*>(&zqb[(16 * w + lo) * 72 +  0 + hi * 8]);
        v8s a1 = *reinterpret_cast<const v8s*>(&zqb[(16 * w + lo) * 72 + 32 + hi * 8]);
#pragma unroll
        for (int ct = 0; ct < 4; ct++) {
            v8s bb0 = *reinterpret_cast<const v8s*>(&w1b[(16 * ct + lo) * 72 +  0 + hi * 8]);
            v8s bb1 = *reinterpret_cast<const v8s*>(&w1b[(16 * ct + lo) * 72 + 32 + hi * 8]);
            v4f acc = (v4f){0.f, 0.f, 0.f, 0.f};
            acc = __builtin_amdgcn_mfma_f32_16x16x32_bf16(a0, bb0, acc, 0, 0, 0);
            acc = __builtin_amdgcn_mfma_f32_16x16x32_bf16(a1, bb1, acc, 0, 0, 0);
            float bias = b1[hc + 16 * ct + lo];
#pragma unroll
            for (int r = 0; r < 4; r++) {
                float hv = fmaxf(acc[r] + bias, 0.f);
                hdb[(16 * w + 4 * hi + r) * 72 + 16 * ct + lo] = f2bf(hv);
            }
        }
        __syncthreads();

#pragma unroll
        for (int kk = 0; kk < 2; kk++) {
            v8s af[4];
#pragma unroll
            for (int rt = 0; rt < 4; rt++)
                af[rt] = *reinterpret_cast<const v8s*>(&hdb[(16 * rt + lo) * 72 + kk * 32 + hi * 8]);
#pragma unroll
            for (int ctl = 0; ctl < 4; ctl++) {
                v8s bf_ = *reinterpret_cast<const v8s*>(&w2b[(64 * w + 16 * ctl + lo) * 72 + kk * 32 + hi * 8]);
#pragma unroll
                for (int rt = 0; rt < 4; rt++)
                    facc[rt][ctl] = __builtin_amdgcn_mfma_f32_16x16x32_bf16(af[rt], bf_, facc[rt][ctl], 0, 0, 0);
            }
        }
    }

#pragma unroll
    for (int ctl = 0; ctl < 4; ctl++) {
        int col = cbase + 64 * w + 16 * ctl + lo;
        float bias = b2[col];
#pragma unroll
        for (int rt = 0; rt < 4; rt++) {
#pragma unroll
            for (int r = 0; r < 4; r++) {
                int row = brow + 16 * rt + 4 * hi + r;
                xr[(size_t)row * NIN + col] = facc[rt][ctl][r] + bias;
            }
        }
    }
}

extern "C" void kernel_launch(void* const* d_in, const int* in_sizes, int n_in,
                              void* d_out, int out_size, void* d_ws, size_t ws_size,
                              hipStream_t stream) {
    (void)in_sizes; (void)n_in; (void)out_size; (void)ws_size;
    const float* x   = (const float*)d_in[0];
    const float* ew1 = (const float*)d_in[1];
    const float* eb1 = (const float*)d_in[2];
    const float* ew2 = (const float*)d_in[3];
    const float* eb2 = (const float*)d_in[4];
    const float* cb  = (const float*)d_in[5];
    const float* dw1 = (const float*)d_in[6];
    const float* db1 = (const float*)d_in[7];
    const float* dw2 = (const float*)d_in[8];
    const float* db2 = (const float*)d_in[9];

    float* out  = (float*)d_out;
    float* part = (float*)d_ws + PART_WS_F;
    unsigned short* w1t = (unsigned short*)((char*)d_ws + W1T_WS_B);
    unsigned short* w2t = (unsigned short*)((char*)d_ws + W2T_WS_B);

    prep_w1t<<<512, 256, 0, stream>>>(dw1, w1t);
    prep_w2t<<<8192, 256, 0, stream>>>(dw2, w2t);
    encvq_kernel<<<NB / 128, 512, 0, stream>>>(x, ew1, eb1, ew2, eb2, cb, out, part);
    loss_kernel<<<1, 64, 0, stream>>>(part, out + LOSS_OFF);
    dec_kernel<<<(NB / 64) * 4, 256, 0, stream>>>(out, w1t, w2t, db1, db2, out + XR_OFF);
}